// Round 5
// baseline (287.665 us; speedup 1.0000x reference)
//
#include <hip/hip_runtime.h>

#define NCLASSES 6

__device__ __forceinline__ float wave_reduce_sum(float v) {
#pragma unroll
    for (int off = 32; off > 0; off >>= 1)
        v += __shfl_down(v, off, 64);
    return v;
}

__device__ __forceinline__ void process4(float4 x, float4 t,
                                         float* __restrict__ sums,
                                         unsigned long long& cpack) {
    float xs[4] = {x.x, x.y, x.z, x.w};
    float ts[4] = {t.x, t.y, t.z, t.w};
#pragma unroll
    for (int j = 0; j < 4; ++j) {
        float ad = fabsf(xs[j] - ts[j]);
        int cls = (int)ts[j];
        cpack += 1ull << (cls * 10);       // packed count histogram, 10b/field
#pragma unroll
        for (int k = 0; k < NCLASSES; ++k)
            sums[k] += (ts[j] == (float)k) ? ad : 0.f;
    }
}

// Fused kernel: streaming partial reduce + last-block-done finalize.
// ws layout: [0..4) unsigned counter (memset to 0 each launch);
//            [256 ...) float partials[nblocks][12] = {sum0..5, cnt0..5}
__global__ void __launch_bounds__(256)
mae_fused_kernel(const float* __restrict__ inputs,
                 const float* __restrict__ targets,
                 unsigned* __restrict__ counter,
                 float* __restrict__ partials,
                 float* __restrict__ out,
                 int n) {
    float sums[NCLASSES] = {0.f, 0.f, 0.f, 0.f, 0.f, 0.f};
    unsigned long long cpack = 0ull;   // per-thread elems <= 1023/field: safe

    const int tid = blockIdx.x * blockDim.x + threadIdx.x;
    const int nthreads = gridDim.x * blockDim.x;
    const int n4 = n >> 2;

    const float4* __restrict__ in4 = reinterpret_cast<const float4*>(inputs);
    const float4* __restrict__ tg4 = reinterpret_cast<const float4*>(targets);

    // R3's wave-chunked x4 unroll: per iteration a wave covers a CONTIGUOUS
    // 4 KB run of each array (4 coalesced float4 loads, 64 float4 apart):
    // 8 loads in flight per thread with tight DRAM page locality.
    const int lane = threadIdx.x & 63;
    const int gwave = tid >> 6;                       // global wave id
    const int step = nthreads * 4;                    // float4 units per iter
    const int n4_main = (n4 / step) * step;

    int i = gwave * 256 + lane;
    for (; i < n4_main; i += step) {
        float4 x0 = in4[i];
        float4 x1 = in4[i + 64];
        float4 x2 = in4[i + 128];
        float4 x3 = in4[i + 192];
        float4 t0 = tg4[i];
        float4 t1 = tg4[i + 64];
        float4 t2 = tg4[i + 128];
        float4 t3 = tg4[i + 192];
        process4(x0, t0, sums, cpack);
        process4(x1, t1, sums, cpack);
        process4(x2, t2, sums, cpack);
        process4(x3, t3, sums, cpack);
    }
    // float4 remainder (n4 not divisible by step)
    for (int r = n4_main + tid; r < n4; r += nthreads)
        process4(in4[r], tg4[r], sums, cpack);

    // scalar tail (n not divisible by 4)
    const int tail_start = n4 << 2;
    for (int s = tail_start + tid; s < n; s += nthreads) {
        float t = targets[s];
        float ad = fabsf(inputs[s] - t);
        int cls = (int)t;
        cpack += 1ull << (cls * 10);
#pragma unroll
        for (int k = 0; k < NCLASSES; ++k)
            sums[k] += (t == (float)k) ? ad : 0.f;
    }

    // Unpack packed counts to floats (once per thread).
    float cnts[NCLASSES];
#pragma unroll
    for (int k = 0; k < NCLASSES; ++k)
        cnts[k] = (float)((cpack >> (10 * k)) & 1023ull);

    // Block reduce: wave shuffle -> LDS across 4 waves.
    __shared__ float lds[4][12];
    const int wave = threadIdx.x >> 6;

#pragma unroll
    for (int k = 0; k < NCLASSES; ++k) {
        float s = wave_reduce_sum(sums[k]);
        float c = wave_reduce_sum(cnts[k]);
        if (lane == 0) {
            lds[wave][k] = s;
            lds[wave][k + NCLASSES] = c;
        }
    }
    __syncthreads();

    if (threadIdx.x < 12) {
        float v = lds[0][threadIdx.x] + lds[1][threadIdx.x] +
                  lds[2][threadIdx.x] + lds[3][threadIdx.x];
        partials[blockIdx.x * 12 + threadIdx.x] = v;
    }

    // ---- last-block-done finalize ----
    __shared__ bool s_is_last;
    __threadfence();               // release: partials visible device-wide
    __syncthreads();
    if (threadIdx.x == 0) {
        unsigned prev = atomicAdd(counter, 1u);
        s_is_last = (prev == (unsigned)(gridDim.x - 1));
    }
    __syncthreads();
    if (!s_is_last) return;

    __threadfence();               // acquire side

    const int nblocks = gridDim.x;
    const float4* __restrict__ p4 = reinterpret_cast<const float4*>(partials);

    float4 a0 = {0.f, 0.f, 0.f, 0.f};
    float4 a1 = {0.f, 0.f, 0.f, 0.f};
    float4 a2 = {0.f, 0.f, 0.f, 0.f};

    for (int b = threadIdx.x; b < nblocks; b += blockDim.x) {
        float4 r0 = p4[b * 3 + 0];
        float4 r1 = p4[b * 3 + 1];
        float4 r2 = p4[b * 3 + 2];
        a0.x += r0.x; a0.y += r0.y; a0.z += r0.z; a0.w += r0.w;
        a1.x += r1.x; a1.y += r1.y; a1.z += r1.z; a1.w += r1.w;
        a2.x += r2.x; a2.y += r2.y; a2.z += r2.z; a2.w += r2.w;
    }

    float acc[12] = {a0.x, a0.y, a0.z, a0.w,
                     a1.x, a1.y, a1.z, a1.w,
                     a2.x, a2.y, a2.z, a2.w};

    __syncthreads();               // safe reuse of lds[][]
#pragma unroll
    for (int k = 0; k < 12; ++k) {
        float v = wave_reduce_sum(acc[k]);
        if (lane == 0) lds[wave][k] = v;
    }
    __syncthreads();

    if (threadIdx.x == 0) {
        float total = 0.f;
#pragma unroll
        for (int c = 0; c < NCLASSES; ++c) {
            float s = lds[0][c] + lds[1][c] + lds[2][c] + lds[3][c];
            float nn = lds[0][c + NCLASSES] + lds[1][c + NCLASSES] +
                       lds[2][c + NCLASSES] + lds[3][c + NCLASSES];
            total += (nn > 0.f) ? (s / nn) : 0.f;
        }
        out[0] = total / (float)NCLASSES;
    }
}

extern "C" void kernel_launch(void* const* d_in, const int* in_sizes, int n_in,
                              void* d_out, int out_size, void* d_ws, size_t ws_size,
                              hipStream_t stream) {
    const float* inputs  = (const float*)d_in[0];
    const float* targets = (const float*)d_in[1];
    float* out = (float*)d_out;

    unsigned* counter = (unsigned*)d_ws;
    float* partials = (float*)((char*)d_ws + 256);   // 16B-aligned, own cacheline

    const int n = in_sizes[0];
    const int NB = 2048;   // 2048 blocks x 4 waves = full 8192-wave residency

    // d_ws is poisoned 0xAA and never re-poisoned between replays: zero the
    // arrival counter every call (async memset is graph-capturable).
    hipMemsetAsync(counter, 0, sizeof(unsigned), stream);

    mae_fused_kernel<<<NB, 256, 0, stream>>>(inputs, targets, counter,
                                             partials, out, n);
}

// Round 6
// 51.969 us; speedup vs baseline: 5.5354x; 5.5354x over previous
//
#include <hip/hip_runtime.h>

#define NCLASSES 6

__device__ __forceinline__ float wave_reduce_sum(float v) {
#pragma unroll
    for (int off = 32; off > 0; off >>= 1)
        v += __shfl_down(v, off, 64);
    return v;
}

__device__ __forceinline__ void process4(float4 x, float4 t,
                                         float* __restrict__ sums,
                                         unsigned long long& cpack) {
    float xs[4] = {x.x, x.y, x.z, x.w};
    float ts[4] = {t.x, t.y, t.z, t.w};
#pragma unroll
    for (int j = 0; j < 4; ++j) {
        float ad = fabsf(xs[j] - ts[j]);
        int cls = (int)ts[j];
        cpack += 1ull << (cls * 10);       // packed count histogram, 10b/field
#pragma unroll
        for (int k = 0; k < NCLASSES; ++k)
            sums[k] += (ts[j] == (float)k) ? ad : 0.f;
    }
}

// Kernel 1: per-block partial {sum, count} per class.
// partials layout: [block][12] = {sum0..sum5, cnt0..cnt5}
__global__ void __launch_bounds__(256)
mae_partial_kernel(const float* __restrict__ inputs,
                   const float* __restrict__ targets,
                   float* __restrict__ partials,
                   int n) {
    float sums[NCLASSES] = {0.f, 0.f, 0.f, 0.f, 0.f, 0.f};
    unsigned long long cpack = 0ull;   // per-thread elems <= 256 -> 10-bit fields safe

    const int tid = blockIdx.x * blockDim.x + threadIdx.x;
    const int nthreads = gridDim.x * blockDim.x;
    const int n4 = n >> 2;

    const float4* __restrict__ in4 = reinterpret_cast<const float4*>(inputs);
    const float4* __restrict__ tg4 = reinterpret_cast<const float4*>(targets);

    // Wave-chunked x4 unroll: per iteration a wave covers a CONTIGUOUS
    // 4 KB run of each array (4 coalesced float4 loads, 64 float4 apart),
    // giving 8 loads in flight per thread with tight DRAM page locality.
    const int lane = threadIdx.x & 63;
    const int gwave = tid >> 6;                       // global wave id
    const int step = nthreads * 4;                    // float4 units per iter
    const int n4_main = (n4 / step) * step;

    int i = gwave * 256 + lane;
    for (; i < n4_main; i += step) {
        float4 x0 = in4[i];
        float4 x1 = in4[i + 64];
        float4 x2 = in4[i + 128];
        float4 x3 = in4[i + 192];
        float4 t0 = tg4[i];
        float4 t1 = tg4[i + 64];
        float4 t2 = tg4[i + 128];
        float4 t3 = tg4[i + 192];
        process4(x0, t0, sums, cpack);
        process4(x1, t1, sums, cpack);
        process4(x2, t2, sums, cpack);
        process4(x3, t3, sums, cpack);
    }
    // float4 remainder (n4 not divisible by step)
    for (int r = n4_main + tid; r < n4; r += nthreads)
        process4(in4[r], tg4[r], sums, cpack);

    // scalar tail (n not divisible by 4)
    const int tail_start = n4 << 2;
    for (int s = tail_start + tid; s < n; s += nthreads) {
        float t = targets[s];
        float ad = fabsf(inputs[s] - t);
        int cls = (int)t;
        cpack += 1ull << (cls * 10);
#pragma unroll
        for (int k = 0; k < NCLASSES; ++k)
            sums[k] += (t == (float)k) ? ad : 0.f;
    }

    // Unpack packed counts to floats (once per thread).
    float cnts[NCLASSES];
#pragma unroll
    for (int k = 0; k < NCLASSES; ++k)
        cnts[k] = (float)((cpack >> (10 * k)) & 1023ull);

    // Block reduce: wave shuffle -> LDS across 4 waves.
    __shared__ float lds[4][12];
    const int wave = threadIdx.x >> 6;

#pragma unroll
    for (int k = 0; k < NCLASSES; ++k) {
        float s = wave_reduce_sum(sums[k]);
        float c = wave_reduce_sum(cnts[k]);
        if (lane == 0) {
            lds[wave][k] = s;
            lds[wave][k + NCLASSES] = c;
        }
    }
    __syncthreads();

    if (threadIdx.x < 12) {
        float v = lds[0][threadIdx.x] + lds[1][threadIdx.x] +
                  lds[2][threadIdx.x] + lds[3][threadIdx.x];
        partials[blockIdx.x * 12 + threadIdx.x] = v;
    }
}

// Kernel 2: deterministic reduce of [nblocks][12] partials -> scalar.
// Single wave, no LDS/barriers: each lane accumulates rows lane, lane+64, ...
// (3 float4 per row), then 12 shuffle-reduces and lane 0 writes the scalar.
__global__ void __launch_bounds__(64)
mae_finalize_kernel(const float* __restrict__ partials, int nblocks,
                    float* __restrict__ out) {
    const float4* __restrict__ p4 = reinterpret_cast<const float4*>(partials);

    float4 a0 = {0.f, 0.f, 0.f, 0.f};
    float4 a1 = {0.f, 0.f, 0.f, 0.f};
    float4 a2 = {0.f, 0.f, 0.f, 0.f};

    const int lane = threadIdx.x;    // 64 threads = 1 wave
#pragma unroll 4
    for (int b = lane; b < nblocks; b += 64) {
        float4 r0 = p4[b * 3 + 0];
        float4 r1 = p4[b * 3 + 1];
        float4 r2 = p4[b * 3 + 2];
        a0.x += r0.x; a0.y += r0.y; a0.z += r0.z; a0.w += r0.w;
        a1.x += r1.x; a1.y += r1.y; a1.z += r1.z; a1.w += r1.w;
        a2.x += r2.x; a2.y += r2.y; a2.z += r2.z; a2.w += r2.w;
    }

    float acc[12] = {a0.x, a0.y, a0.z, a0.w,
                     a1.x, a1.y, a1.z, a1.w,
                     a2.x, a2.y, a2.z, a2.w};

    float red[12];
#pragma unroll
    for (int k = 0; k < 12; ++k)
        red[k] = wave_reduce_sum(acc[k]);

    if (lane == 0) {
        float total = 0.f;
#pragma unroll
        for (int c = 0; c < NCLASSES; ++c) {
            float s = red[c];
            float nn = red[c + NCLASSES];
            total += (nn > 0.f) ? (s / nn) : 0.f;
        }
        out[0] = total / (float)NCLASSES;
    }
}

extern "C" void kernel_launch(void* const* d_in, const int* in_sizes, int n_in,
                              void* d_out, int out_size, void* d_ws, size_t ws_size,
                              hipStream_t stream) {
    const float* inputs  = (const float*)d_in[0];
    const float* targets = (const float*)d_in[1];
    float* out = (float*)d_out;
    float* partials = (float*)d_ws;

    const int n = in_sizes[0];
    const int NB = 2048;   // 2048 blocks x 4 waves = full 8192-wave residency

    mae_partial_kernel<<<NB, 256, 0, stream>>>(inputs, targets, partials, n);
    mae_finalize_kernel<<<1, 64, 0, stream>>>(partials, NB, out);
}